// Round 5
// baseline (114.601 us; speedup 1.0000x reference)
//
#include <hip/hip_runtime.h>
#include <hip/hip_bf16.h>

#define BH_N 8192
#define BH_D 128
#define BH_NC 10
#define BH_MARGIN 1.0f
#define NSEG 4
#define MAXTILES (BH_N / 32 + BH_NC)
#define NCHUNK 8
#define CHROWS (BH_N / NCHUNK)   // 1024

typedef __attribute__((ext_vector_type(8)))  short bf16x8;
typedef __attribute__((ext_vector_type(16))) float f32x16;

#define OFF_R(r) (((r) & 3) + 8 * ((r) >> 2))   // C/D row offset for 32x32 MFMA (plus 4*(lane>>5))

__device__ __forceinline__ unsigned short f2bf(float f) {
    unsigned u = __float_as_uint(f);
    u += 0x7fffu + ((u >> 16) & 1u);
    return (unsigned short)(u >> 16);
}
__device__ __forceinline__ float bf2f(short h) {
    return __uint_as_float(((unsigned)(unsigned short)h) << 16);
}

// ---------------- Kernel 1: identity-order convert+x2 (blocks 0..31) + class-chunk M slabs (32..111) ----------------
__global__ __launch_bounds__(1024) void bh_prep(const float* __restrict__ E,
                                                const int* __restrict__ labels,
                                                unsigned short* __restrict__ Es,
                                                float* __restrict__ x2s,
                                                float* __restrict__ Mpart,   // [NCHUNK][NC][128]
                                                float* __restrict__ sxpart,  // [NCHUNK][NC]
                                                int* __restrict__ dposU) {
    const int t = threadIdx.x;
    const int b = blockIdx.x;
    if (b < 32) {
        // 256 rows/block, 4 threads per row (sub = dim-slice of 32)
        const int lr = t >> 2, sub = t & 3;
        const int row = b * 256 + lr;
        const float4* ep = (const float4*)(E + (size_t)row * BH_D + sub * 32);
        float4 v[8];
#pragma unroll
        for (int k = 0; k < 8; k++) v[k] = ep[k];
        float s = 0.0f;
#pragma unroll
        for (int k = 0; k < 8; k++)
            s += v[k].x * v[k].x + v[k].y * v[k].y + v[k].z * v[k].z + v[k].w * v[k].w;
        s += __shfl_xor(s, 1); s += __shfl_xor(s, 2);
        if (sub == 0) x2s[row] = s;
        ushort4* op = (ushort4*)(Es + (size_t)row * BH_D + sub * 32);
#pragma unroll
        for (int k = 0; k < 8; k++) {
            ushort4 h;
            h.x = f2bf(v[k].x); h.y = f2bf(v[k].y); h.z = f2bf(v[k].z); h.w = f2bf(v[k].w);
            op[k] = h;
        }
        if (t < 256) dposU[b * 256 + t] = 0;
    } else {
        // class-chunk scan: block handles class c over rows [chunk*1024, +1024)
        const int idx = b - 32;
        const int c = idx >> 3, chunk = idx & 7;
        const int lr = t >> 2, sub = t & 3;
        const int lane = t & 63;
        float acc[32];
#pragma unroll
        for (int d = 0; d < 32; d++) acc[d] = 0.0f;
        float sx = 0.0f;
#pragma unroll
        for (int rr = 0; rr < 4; rr++) {
            const int row = chunk * CHROWS + rr * 256 + lr;
            if (labels[row] == c) {
                const float4* ep = (const float4*)(E + (size_t)row * BH_D + sub * 32);
#pragma unroll
                for (int k = 0; k < 8; k++) {
                    const float4 v = ep[k];
                    acc[k * 4 + 0] += v.x; acc[k * 4 + 1] += v.y;
                    acc[k * 4 + 2] += v.z; acc[k * 4 + 3] += v.w;
                    sx += v.x * v.x + v.y * v.y + v.z * v.z + v.w * v.w;
                }
            }
        }
        __shared__ float Msh[BH_D];
        __shared__ float sxsh;
        if (t < BH_D) Msh[t] = 0.0f;
        if (t == 0) sxsh = 0.0f;
        __syncthreads();
        // reduce the 16 rows within each wave (xor 4..32 collapses lr-within-wave), then LDS atomic
#pragma unroll
        for (int d = 0; d < 32; d++) {
            float a = acc[d];
            a += __shfl_xor(a, 4); a += __shfl_xor(a, 8);
            a += __shfl_xor(a, 16); a += __shfl_xor(a, 32);
            if ((lane & 60) == 0) atomicAdd(&Msh[sub * 32 + d], a);
        }
        sx += __shfl_xor(sx, 1); sx += __shfl_xor(sx, 2);
        sx += __shfl_xor(sx, 4); sx += __shfl_xor(sx, 8);
        sx += __shfl_xor(sx, 16); sx += __shfl_xor(sx, 32);
        if (lane == 0) atomicAdd(&sxsh, sx);
        __syncthreads();
        if (t < BH_D) Mpart[((size_t)chunk * BH_NC + c) * BH_D + t] = Msh[t];
        if (t == 0) sxpart[chunk * BH_NC + c] = sxsh;
    }
}

// ---------------- Kernel 2: counting sort (LDS-staged scatter) + M/sumx2 slab reduce + out zero ----------------
__global__ __launch_bounds__(1024) void bh_sortk(const int* __restrict__ labels,
                                                 int* __restrict__ sidx,
                                                 int* __restrict__ cstart,
                                                 const float* __restrict__ Mpart,
                                                 const float* __restrict__ sxpart,
                                                 float* __restrict__ M,
                                                 float* __restrict__ sumx2,
                                                 float* __restrict__ out) {
    const int t = threadIdx.x;
    // slab reduce (independent of sort flow)
    for (int i = t; i < BH_NC * BH_D; i += 1024) {
        float s = 0.0f;
#pragma unroll
        for (int ch = 0; ch < NCHUNK; ch++) s += Mpart[(size_t)ch * BH_NC * BH_D + i];
        M[i] = s;
    }
    if (t < BH_NC) {
        float s = 0.0f;
#pragma unroll
        for (int ch = 0; ch < NCHUNK; ch++) s += sxpart[ch * BH_NC + t];
        sumx2[t] = s;
    }
    if (t == 0) out[0] = 0.0f;

    const int lane = t & 63, w = t >> 6;   // 16 waves
    const int4* lp = (const int4*)labels;
    const int4 a = lp[t * 2], b = lp[t * 2 + 1];
    int L[8] = {a.x, a.y, a.z, a.w, b.x, b.y, b.z, b.w};

    int lh[BH_NC];
#pragma unroll
    for (int c = 0; c < BH_NC; c++) lh[c] = 0;
#pragma unroll
    for (int k = 0; k < 8; k++) {
#pragma unroll
        for (int c = 0; c < BH_NC; c++) lh[c] += (L[k] == c);
    }
    int inc[BH_NC];
#pragma unroll
    for (int c = 0; c < BH_NC; c++) inc[c] = lh[c];
#pragma unroll
    for (int m = 1; m < 64; m <<= 1) {
#pragma unroll
        for (int c = 0; c < BH_NC; c++) {
            const int o = __shfl_up(inc[c], m);
            if (lane >= m) inc[c] += o;
        }
    }
    __shared__ int wtot[16][BH_NC];
    __shared__ int wpref[16][BH_NC];
    __shared__ int ctot[BH_NC];
    __shared__ int cst[BH_NC + 1];
    __shared__ int sid[BH_N];   // 32 KB staging
    if (lane == 63) {
#pragma unroll
        for (int c = 0; c < BH_NC; c++) wtot[w][c] = inc[c];
    }
    __syncthreads();
    if (t < BH_NC) {
        int run = 0;
#pragma unroll
        for (int w2 = 0; w2 < 16; w2++) { wpref[w2][t] = run; run += wtot[w2][t]; }
        ctot[t] = run;
    }
    __syncthreads();
    if (t == 0) {
        int run = 0;
#pragma unroll
        for (int c = 0; c < BH_NC; c++) { cst[c] = run; run += ctot[c]; }
        cst[BH_NC] = run;
#pragma unroll
        for (int c = 0; c <= BH_NC; c++) cstart[c] = cst[c];
    }
    __syncthreads();
    int wpre[BH_NC];
#pragma unroll
    for (int c = 0; c < BH_NC; c++) wpre[c] = cst[c] + wpref[w][c] + inc[c] - lh[c];
#pragma unroll
    for (int k = 0; k < 8; k++) {
        const int j = t * 8 + k;
        const int Lk = L[k];
        int pos = 0;
#pragma unroll
        for (int c = 0; c < BH_NC; c++) pos += (Lk == c) ? wpre[c] : 0;
        sid[pos] = j;
#pragma unroll
        for (int c = 0; c < BH_NC; c++) wpre[c] += (Lk == c);
    }
    __syncthreads();
    for (int i = t; i < BH_N; i += 1024) sidx[i] = sid[i];   // coalesced flush
}

// ---------------- Kernel 3: same-class pairwise max (d_pos) — gathered rows, prefetched ----------------
__global__ __launch_bounds__(64) void bh_dpos(const unsigned short* __restrict__ Es,
                                              const float* __restrict__ x2s,
                                              const int* __restrict__ sidx,
                                              const int* __restrict__ cstart,
                                              int* __restrict__ dposU) {
    const int tile = blockIdx.x / NSEG;
    const int seg  = blockIdx.x % NSEG;
    int cs[BH_NC + 1];
#pragma unroll
    for (int c = 0; c <= BH_NC; c++) cs[c] = cstart[c];
    int c = -1, t0 = 0, base = 0;
#pragma unroll
    for (int cc = 0; cc < BH_NC; cc++) {
        const int len = cs[cc + 1] - cs[cc];
        const int nt = (len + 31) >> 5;
        if (c < 0 && tile < base + nt) { c = cc; t0 = tile - base; }
        base += nt;
    }
    if (c < 0) return;
    const int c0 = cs[c], c1 = cs[c + 1], len = c1 - c0;
    const int rb = c0 + t0 * 32;
    const int nch = (len + 31) >> 5;
    const int per = (nch + NSEG - 1) / NSEG;
    const int jb0 = c0 + seg * per * 32;
    if (jb0 >= c1) return;
    const int jb1 = min(jb0 + per * 32, c1);

    const int lane = threadIdx.x;
    const int cid = lane & 31, half = lane >> 5;
    const int rowbase = rb + 4 * half;

    bf16x8 afrag[8];
    {
        const int ar = sidx[min(rb + cid, BH_N - 1)];
        const unsigned short* arow = Es + (size_t)ar * BH_D + half * 8;
#pragma unroll
        for (int ks = 0; ks < 8; ks++) afrag[ks] = *(const bf16x8*)(arow + ks * 16);
    }
    float xr[16];
#pragma unroll
    for (int r = 0; r < 16; r++) xr[r] = x2s[sidx[min(rowbase + OFF_R(r), BH_N - 1)]];

    float dpos[16];
#pragma unroll
    for (int r = 0; r < 16; r++) dpos[r] = 0.0f;

    // register double-buffered B prefetch (branchless clamped addressing)
    int jor = sidx[min(jb0 + cid, c1 - 1)];
    bf16x8 bcur[8];
    {
        const unsigned short* brow = Es + (size_t)jor * BH_D + half * 8;
#pragma unroll
        for (int ks = 0; ks < 8; ks++) bcur[ks] = *(const bf16x8*)(brow + ks * 16);
    }
    float xc = x2s[jor];

    for (int jb = jb0; jb < jb1; jb += 32) {
        const int jorn = sidx[min(jb + 32 + cid, c1 - 1)];
        bf16x8 bnxt[8];
        {
            const unsigned short* brow = Es + (size_t)jorn * BH_D + half * 8;
#pragma unroll
            for (int ks = 0; ks < 8; ks++) bnxt[ks] = *(const bf16x8*)(brow + ks * 16);
        }
        const float xcn = x2s[jorn];

        f32x16 acc = {0.0f, 0.0f, 0.0f, 0.0f, 0.0f, 0.0f, 0.0f, 0.0f,
                      0.0f, 0.0f, 0.0f, 0.0f, 0.0f, 0.0f, 0.0f, 0.0f};
#pragma unroll
        for (int ks = 0; ks < 8; ks++)
            acc = __builtin_amdgcn_mfma_f32_32x32x16_bf16(afrag[ks], bcur[ks], acc, 0, 0, 0);

        const bool vm = (jb + cid) < jb1;
#pragma unroll
        for (int r = 0; r < 16; r++) {
            const float dd = fmaxf(fmaf(-2.0f, acc[r], xr[r] + xc), 0.0f);
            const bool rowin = (rowbase + OFF_R(r)) < c1;
            dpos[r] = fmaxf(dpos[r], (vm && rowin) ? dd : 0.0f);
        }
#pragma unroll
        for (int ks = 0; ks < 8; ks++) bcur[ks] = bnxt[ks];
        xc = xcn;
    }
#pragma unroll
    for (int r = 0; r < 16; r++) {
#pragma unroll
        for (int m = 1; m < 32; m <<= 1) dpos[r] = fmaxf(dpos[r], __shfl_xor(dpos[r], m));
    }
    if (cid == 0) {
#pragma unroll
        for (int r = 0; r < 16; r++) {
            const int row = rowbase + OFF_R(r);
            if (row < c1) atomicMax(&dposU[row], __float_as_int(dpos[r]));
        }
    }
}

// ---------------- Kernel 4: per-lane anchors — analytic S, k*, d_neg, loss ----------------
__global__ __launch_bounds__(64) void bh_select(const unsigned short* __restrict__ Es,
                                                const float* __restrict__ x2s,
                                                const int* __restrict__ sidx,
                                                const int* __restrict__ cstart,
                                                const float* __restrict__ M,
                                                const float* __restrict__ sumx2,
                                                const int* __restrict__ dposU,
                                                float* __restrict__ out) {
    const int lane = threadIdx.x;
    const int spos = blockIdx.x * 64 + lane;

    int cs[BH_NC + 1];
#pragma unroll
    for (int c = 0; c <= BH_NC; c++) cs[c] = cstart[c];

    const int oi = sidx[spos];
    bf16x8 u0[16];
    const unsigned short* rp = Es + (size_t)oi * BH_D;
#pragma unroll
    for (int k = 0; k < 16; k++) u0[k] = *(const bf16x8*)(rp + k * 8);

    float dc[BH_NC];
#pragma unroll
    for (int c = 0; c < BH_NC; c++) dc[c] = 0.0f;
#pragma unroll
    for (int k = 0; k < 16; k++) {
        float ef[8];
#pragma unroll
        for (int d = 0; d < 8; d++) ef[d] = bf2f(u0[k][d]);
#pragma unroll
        for (int c = 0; c < BH_NC; c++) {
            const float4 m0 = *(const float4*)(M + (size_t)c * BH_D + k * 8);
            const float4 m1 = *(const float4*)(M + (size_t)c * BH_D + k * 8 + 4);
            dc[c] += ef[0] * m0.x + ef[1] * m0.y + ef[2] * m0.z + ef[3] * m0.w
                   + ef[4] * m1.x + ef[5] * m1.y + ef[6] * m1.z + ef[7] * m1.w;
        }
    }

    const float x2i = x2s[oi];
    float T = 0.0f, Sk[BH_NC];
#pragma unroll
    for (int c = 0; c < BH_NC; c++) {
        Sk[c] = (float)(cs[c + 1] - cs[c]) * x2i + sumx2[c] - 2.0f * dc[c];
        T += Sk[c];
    }
    int kstar = 0; float best = T - Sk[0];
#pragma unroll
    for (int c = 1; c < BH_NC; c++) {
        const float nd = T - Sk[c];
        if (nd < best) { best = nd; kstar = c; }
    }

    int a = 0;
#pragma unroll
    for (int c = 1; c < BH_NC; c++) a += (spos >= cs[c]);
    const int p = (kstar < cs[a]) ? kstar : (cs[a + 1] + (kstar - cs[a]));
    const int oj = sidx[p];

    const unsigned short* qp = Es + (size_t)oj * BH_D;
    float dp = 0.0f;
#pragma unroll
    for (int k = 0; k < 16; k++) {
        const bf16x8 u1 = *(const bf16x8*)(qp + k * 8);
#pragma unroll
        for (int d = 0; d < 8; d++) dp = fmaf(bf2f(u0[k][d]), bf2f(u1[d]), dp);
    }
    const float dneg = fmaxf(x2i + x2s[oj] - 2.0f * dp, 0.0f);

    const float dposv = __int_as_float(dposU[spos]);
    float loss = fmaxf(dposv - dneg + BH_MARGIN, 0.0f);
#pragma unroll
    for (int m = 1; m < 64; m <<= 1) loss += __shfl_xor(loss, m);
    if (lane == 0) atomicAdd(out, loss * (1.0f / (float)BH_N));
}

extern "C" void kernel_launch(void* const* d_in, const int* in_sizes, int n_in,
                              void* d_out, int out_size, void* d_ws, size_t ws_size,
                              hipStream_t stream) {
    const float* E = (const float*)d_in[0];
    const int* labels = (const int*)d_in[1];
    float* out = (float*)d_out;

    unsigned short* Es = (unsigned short*)d_ws;                  // N*D bf16 (2 MB)
    float* x2s   = (float*)(Es + (size_t)BH_N * BH_D);           // N
    float* M     = x2s + BH_N;                                   // 1280
    float* sumx2 = M + BH_NC * BH_D;                             // 16 (pad)
    float* Mpart = sumx2 + 16;                                   // 8*10*128
    float* sxpart= Mpart + (size_t)NCHUNK * BH_NC * BH_D;        // 128 (pad)
    int*   dposU = (int*)(sxpart + 128);                         // N
    int*   sidx  = dposU + BH_N;                                 // N
    int*   cstart= sidx + BH_N;                                  // 16

    bh_prep<<<112, 1024, 0, stream>>>(E, labels, Es, x2s, Mpart, sxpart, dposU);
    bh_sortk<<<1, 1024, 0, stream>>>(labels, sidx, cstart, Mpart, sxpart, M, sumx2, out);
    bh_dpos<<<MAXTILES * NSEG, 64, 0, stream>>>(Es, x2s, sidx, cstart, dposU);
    bh_select<<<BH_N / 64, 64, 0, stream>>>(Es, x2s, sidx, cstart, M, sumx2, dposU, out);
}